// Round 1
// baseline (803.343 us; speedup 1.0000x reference)
//
#include <hip/hip_runtime.h>
#include <math.h>

#define N_NODES 100000
#define N_EDGES 1600000

// ---------------- CSR build ----------------
__global__ void count_kernel(const int* __restrict__ eidx, int* __restrict__ cnt) {
    int e = blockIdx.x * 256 + threadIdx.x;
    if (e < N_EDGES) atomicAdd(&cnt[eidx[N_EDGES + e]], 1);
}

__global__ void dinv_kernel(const int* __restrict__ cnt, float* __restrict__ dinv) {
    int i = blockIdx.x * 256 + threadIdx.x;
    if (i < N_NODES) dinv[i] = rsqrtf(1.0f + (float)cnt[i]);
}

// exclusive scan of cnt -> rowp (per-block partial), block totals -> bsum
__global__ void scan1_kernel(const int* __restrict__ cnt, int* __restrict__ rowp,
                             int* __restrict__ bsum) {
    __shared__ int sh[256];
    int tid = threadIdx.x;
    int base = blockIdx.x * 1024 + tid * 4;
    int v[4]; int s = 0;
    #pragma unroll
    for (int j = 0; j < 4; j++) { int idx = base + j; v[j] = (idx < N_NODES) ? cnt[idx] : 0; s += v[j]; }
    sh[tid] = s; __syncthreads();
    for (int off = 1; off < 256; off <<= 1) {
        int add = (tid >= off) ? sh[tid - off] : 0;
        __syncthreads();
        sh[tid] += add;
        __syncthreads();
    }
    int incl = sh[tid];
    if (tid == 255) bsum[blockIdx.x] = incl;
    int run = incl - s;
    #pragma unroll
    for (int j = 0; j < 4; j++) { int idx = base + j; if (idx < N_NODES) rowp[idx] = run; run += v[j]; }
}

__global__ void scan2_kernel(int* __restrict__ bsum, int nb) {
    __shared__ int sh[128];
    int tid = threadIdx.x;
    int v = (tid < nb) ? bsum[tid] : 0;
    sh[tid] = v; __syncthreads();
    for (int off = 1; off < 128; off <<= 1) {
        int add = (tid >= off) ? sh[tid - off] : 0;
        __syncthreads();
        sh[tid] += add;
        __syncthreads();
    }
    if (tid < nb) bsum[tid] = sh[tid] - v;   // exclusive
}

__global__ void scan3_kernel(int* __restrict__ rowp, const int* __restrict__ bsum) {
    int i = blockIdx.x * 256 + threadIdx.x;
    if (i < N_NODES) rowp[i] += bsum[i >> 10];
}

// after this, rowp[i] == end offset; start = rowp[i] - cnt[i]
__global__ void scatter_kernel(const int* __restrict__ eidx, int* __restrict__ rowp,
                               int* __restrict__ esrc) {
    int e = blockIdx.x * 256 + threadIdx.x;
    if (e < N_EDGES) {
        int d = eidx[N_EDGES + e];
        int slot = atomicAdd(&rowp[d], 1);
        esrc[slot] = eidx[e];
    }
}

// ---------------- encoder: h = relu(x @ W_enc + b) ----------------
__global__ __launch_bounds__(256) void enc_kernel(const float* __restrict__ x,
                                                  const float* __restrict__ W,
                                                  const float* __restrict__ b,
                                                  float* __restrict__ h) {
    __shared__ float Wl[16 * 128];
    int tid = threadIdx.x;
    for (int i = tid; i < 16 * 128; i += 256) Wl[i] = W[i];
    __syncthreads();
    int col = tid & 127;
    int rl = tid >> 7;          // 0/1
    float bias = b[col];
    int row0 = blockIdx.x * 16;
    for (int it = 0; it < 8; it++) {
        int row = row0 + it * 2 + rl;
        if (row < N_NODES) {
            float acc = bias;
            #pragma unroll
            for (int k = 0; k < 16; k++) acc += x[row * 16 + k] * Wl[k * 128 + col];
            h[row * 128 + col] = fmaxf(acc, 0.0f);
        }
    }
}

// ---------------- f32 vector GEMM: out[N][NOUT] = (relu?)h[N][128] @ W[128][NOUT] ----------------
template <int NOUT, bool RELU_IN>
__global__ __launch_bounds__(256) void gemm_kernel(const float* __restrict__ h,
                                                   const float* __restrict__ W,
                                                   float* __restrict__ out) {
    constexpr int CT = NOUT / 4;        // col-threads (each does 4 cols)
    constexpr int RT = 256 / CT;        // row-threads (each does 4 rows)
    constexpr int BM = RT * 4;          // rows per block
    __shared__ float Wl[128 * NOUT];
    __shared__ float hs[BM * 128];
    int tid = threadIdx.x;
    for (int i = tid; i < 128 * NOUT; i += 256) Wl[i] = W[i];
    int row0 = blockIdx.x * BM;
    for (int i = tid; i < BM * 128; i += 256) {
        int r = i >> 7, k = i & 127;
        int row = row0 + r;
        float v = (row < N_NODES) ? h[row * 128 + k] : 0.0f;
        if (RELU_IN) v = fmaxf(v, 0.0f);
        hs[i] = v;
    }
    __syncthreads();
    int c0 = (tid % CT) * 4;
    int r0 = (tid / CT) * 4;
    float acc[4][4] = {};
    for (int kb = 0; kb < 128; kb += 4) {
        float4 hv[4];
        #pragma unroll
        for (int i = 0; i < 4; i++) hv[i] = *(const float4*)&hs[(r0 + i) * 128 + kb];
        float4 wv[4];
        #pragma unroll
        for (int j = 0; j < 4; j++) wv[j] = *(const float4*)&Wl[(kb + j) * NOUT + c0];
        #pragma unroll
        for (int i = 0; i < 4; i++) {
            const float* hp = (const float*)&hv[i];
            #pragma unroll
            for (int j = 0; j < 4; j++) {
                float hk = hp[j];
                acc[i][0] += hk * wv[j].x;
                acc[i][1] += hk * wv[j].y;
                acc[i][2] += hk * wv[j].z;
                acc[i][3] += hk * wv[j].w;
            }
        }
    }
    #pragma unroll
    for (int i = 0; i < 4; i++) {
        int row = row0 + r0 + i;
        if (row < N_NODES) {
            float4 o = make_float4(acc[i][0], acc[i][1], acc[i][2], acc[i][3]);
            *(float4*)&out[row * NOUT + c0] = o;
        }
    }
}

// ---------------- aggregation: out[i] = b + dinv_i^2*hw[i] + sum_{e:dst=i} dinv_s*dinv_i*hw[s]
// one wave per node; F/64 floats per lane
template <int F>
__global__ __launch_bounds__(256) void agg_kernel(const float* __restrict__ hw,
                                                  const int* __restrict__ esrc,
                                                  const int* __restrict__ rowp_end,
                                                  const int* __restrict__ cnt,
                                                  const float* __restrict__ dinv,
                                                  const float* __restrict__ bias,
                                                  float* __restrict__ out) {
    int wave = threadIdx.x >> 6;
    int lane = threadIdx.x & 63;
    int i = blockIdx.x * 4 + wave;
    if (i >= N_NODES) return;
    float di = dinv[i];
    int end = rowp_end[i];
    int start = end - cnt[i];
    if (F == 128) {
        float2 hv = *(const float2*)&hw[(size_t)i * 128 + lane * 2];
        float w = di * di;
        float acc0 = bias[lane * 2] + w * hv.x;
        float acc1 = bias[lane * 2 + 1] + w * hv.y;
        for (int e = start; e < end; e++) {
            int s = esrc[e];
            float wgt = dinv[s] * di;
            float2 v = *(const float2*)&hw[(size_t)s * 128 + lane * 2];
            acc0 += wgt * v.x;
            acc1 += wgt * v.y;
        }
        *(float2*)&out[(size_t)i * 128 + lane * 2] = make_float2(acc0, acc1);
    } else {
        float w = di * di;
        float acc0 = bias[lane] + w * hw[(size_t)i * 64 + lane];
        for (int e = start; e < end; e++) {
            int s = esrc[e];
            acc0 += dinv[s] * di * hw[(size_t)s * 64 + lane];
        }
        out[(size_t)i * 64 + lane] = acc0;
    }
}

// ---------------- per-node epilogue: a,c lookup tables + voltage output ----------------
__global__ __launch_bounds__(256) void node_kernel(const float* __restrict__ h2,
                                                   const float* __restrict__ Wsw,
                                                   const float* __restrict__ Wv,
                                                   const float* __restrict__ bv,
                                                   float* __restrict__ aarr,
                                                   float* __restrict__ carr,
                                                   float* __restrict__ outv) {
    int wave = threadIdx.x >> 6, lane = threadIdx.x & 63;
    int i = blockIdx.x * 4 + wave;
    if (i >= N_NODES) return;
    float h = fmaxf(h2[(size_t)i * 64 + lane], 0.0f);
    float pa = h * Wsw[lane];
    float pc = h * Wsw[64 + lane];
    float pv = h * Wv[lane];
    #pragma unroll
    for (int m = 32; m >= 1; m >>= 1) {
        pa += __shfl_xor(pa, m, 64);
        pc += __shfl_xor(pc, m, 64);
        pv += __shfl_xor(pv, m, 64);
    }
    if (lane == 0) {
        aarr[i] = pa;
        carr[i] = pc;
        float v = 1.0f / (1.0f + expf(-(pv + bv[0])));
        float t = 0.9f + 0.2f * v;
        float vw = fminf(fmaxf(t * t, 0.81f), 1.21f);
        outv[i] = sqrtf(vw);
    }
}

// ---------------- per-edge switch scores ----------------
__global__ void edge_kernel(const int* __restrict__ eidx, const float* __restrict__ aarr,
                            const float* __restrict__ carr, const float* __restrict__ bsw,
                            float* __restrict__ out) {
    int e = blockIdx.x * 256 + threadIdx.x;
    if (e < N_EDGES) {
        int s = eidx[e], d = eidx[N_EDGES + e];
        float z = aarr[s] + carr[d] + bsw[0];
        float y = 1.0f / (1.0f + expf(-z));
        out[e] = fminf(fmaxf(y, 0.0f), 1.0f);
    }
}

extern "C" void kernel_launch(void* const* d_in, const int* in_sizes, int n_in,
                              void* d_out, int out_size, void* d_ws, size_t ws_size,
                              hipStream_t stream) {
    const float* x     = (const float*)d_in[0];
    const int*   eidx  = (const int*)d_in[1];
    const float* W_enc = (const float*)d_in[2];
    const float* b_enc = (const float*)d_in[3];
    const float* W_g0  = (const float*)d_in[4];
    const float* b_g0  = (const float*)d_in[5];
    const float* W_g1  = (const float*)d_in[6];
    const float* b_g1  = (const float*)d_in[7];
    const float* W_sw  = (const float*)d_in[8];
    const float* b_sw  = (const float*)d_in[9];
    const float* W_v   = (const float*)d_in[10];
    const float* b_v   = (const float*)d_in[11];
    float* out = (float*)d_out;

    char* ws = (char*)d_ws;
    size_t off = 0;
    auto alloc = [&](size_t bytes) {
        void* p = ws + off;
        off = (off + bytes + 255) & ~(size_t)255;
        return p;
    };
    float* bufA = (float*)alloc((size_t)N_NODES * 128 * 4);
    float* bufB = (float*)alloc((size_t)N_NODES * 128 * 4);
    int*   cnt  = (int*)alloc((size_t)N_NODES * 4);
    int*   rowp = (int*)alloc((size_t)N_NODES * 4);
    float* dinv = (float*)alloc((size_t)N_NODES * 4);
    float* aarr = (float*)alloc((size_t)N_NODES * 4);
    float* carr = (float*)alloc((size_t)N_NODES * 4);
    int*   esrc = (int*)alloc((size_t)N_EDGES * 4);
    int*   bsum = (int*)alloc(128 * 4);

    hipMemsetAsync(cnt, 0, (size_t)N_NODES * 4, stream);
    count_kernel<<<(N_EDGES + 255) / 256, 256, 0, stream>>>(eidx, cnt);
    dinv_kernel<<<(N_NODES + 255) / 256, 256, 0, stream>>>(cnt, dinv);
    int nb = (N_NODES + 1023) / 1024;
    scan1_kernel<<<nb, 256, 0, stream>>>(cnt, rowp, bsum);
    scan2_kernel<<<1, 128, 0, stream>>>(bsum, nb);
    scan3_kernel<<<(N_NODES + 255) / 256, 256, 0, stream>>>(rowp, bsum);
    scatter_kernel<<<(N_EDGES + 255) / 256, 256, 0, stream>>>(eidx, rowp, esrc);

    enc_kernel<<<(N_NODES + 15) / 16, 256, 0, stream>>>(x, W_enc, b_enc, bufA);
    gemm_kernel<128, false><<<(N_NODES + 31) / 32, 256, 0, stream>>>(bufA, W_g0, bufB);
    agg_kernel<128><<<(N_NODES + 3) / 4, 256, 0, stream>>>(bufB, esrc, rowp, cnt, dinv, b_g0, bufA);
    gemm_kernel<64, true><<<(N_NODES + 63) / 64, 256, 0, stream>>>(bufA, W_g1, bufB);
    agg_kernel<64><<<(N_NODES + 3) / 4, 256, 0, stream>>>(bufB, esrc, rowp, cnt, dinv, b_g1, bufA);
    node_kernel<<<(N_NODES + 3) / 4, 256, 0, stream>>>(bufA, W_sw, W_v, b_v, aarr, carr, out + N_EDGES);
    edge_kernel<<<(N_EDGES + 255) / 256, 256, 0, stream>>>(eidx, aarr, carr, b_sw, out);
}

// Round 2
// 563.181 us; speedup vs baseline: 1.4264x; 1.4264x over previous
//
#include <hip/hip_runtime.h>
#include <math.h>

#define N_NODES 100000
#define N_EDGES 1600000

// ---------- bf16 helpers (packed pair in a uint: low 16 = even elem) ----------
__device__ inline float bf_lo(unsigned v) { union { unsigned u; float f; } c; c.u = v << 16; return c.f; }
__device__ inline float bf_hi(unsigned v) { union { unsigned u; float f; } c; c.u = v & 0xffff0000u; return c.f; }
__device__ inline float bf2f(unsigned short h) { union { unsigned u; float f; } c; c.u = ((unsigned)h) << 16; return c.f; }
__device__ inline unsigned short f2bf(float f) {
    union { float f; unsigned u; } c; c.f = f;
    unsigned r = c.u + 0x7fffu + ((c.u >> 16) & 1u);   // round-nearest-even
    return (unsigned short)(r >> 16);
}
__device__ inline unsigned pack2(float a, float b) {
    return (unsigned)f2bf(a) | ((unsigned)f2bf(b) << 16);
}

// ---------------- CSR build ----------------
__global__ void count_kernel(const int* __restrict__ eidx, int* __restrict__ cnt) {
    int e = blockIdx.x * 256 + threadIdx.x;
    if (e < N_EDGES) atomicAdd(&cnt[eidx[N_EDGES + e]], 1);
}

__global__ void dinv_kernel(const int* __restrict__ cnt, float* __restrict__ dinv) {
    int i = blockIdx.x * 256 + threadIdx.x;
    if (i < N_NODES) dinv[i] = rsqrtf(1.0f + (float)cnt[i]);
}

__global__ void scan1_kernel(const int* __restrict__ cnt, int* __restrict__ rowp,
                             int* __restrict__ bsum) {
    __shared__ int sh[256];
    int tid = threadIdx.x;
    int base = blockIdx.x * 1024 + tid * 4;
    int v[4]; int s = 0;
    #pragma unroll
    for (int j = 0; j < 4; j++) { int idx = base + j; v[j] = (idx < N_NODES) ? cnt[idx] : 0; s += v[j]; }
    sh[tid] = s; __syncthreads();
    for (int off = 1; off < 256; off <<= 1) {
        int add = (tid >= off) ? sh[tid - off] : 0;
        __syncthreads();
        sh[tid] += add;
        __syncthreads();
    }
    int incl = sh[tid];
    if (tid == 255) bsum[blockIdx.x] = incl;
    int run = incl - s;
    #pragma unroll
    for (int j = 0; j < 4; j++) { int idx = base + j; if (idx < N_NODES) rowp[idx] = run; run += v[j]; }
}

__global__ void scan2_kernel(int* __restrict__ bsum, int nb) {
    __shared__ int sh[128];
    int tid = threadIdx.x;
    int v = (tid < nb) ? bsum[tid] : 0;
    sh[tid] = v; __syncthreads();
    for (int off = 1; off < 128; off <<= 1) {
        int add = (tid >= off) ? sh[tid - off] : 0;
        __syncthreads();
        sh[tid] += add;
        __syncthreads();
    }
    if (tid < nb) bsum[tid] = sh[tid] - v;   // exclusive
}

__global__ void scan3_kernel(int* __restrict__ rowp, const int* __restrict__ bsum) {
    int i = blockIdx.x * 256 + threadIdx.x;
    if (i < N_NODES) rowp[i] += bsum[i >> 10];
}

// after this, rowp[i] == end offset; start = rowp[i] - cnt[i]
__global__ void scatter_kernel(const int* __restrict__ eidx, int* __restrict__ rowp,
                               int* __restrict__ esrc) {
    int e = blockIdx.x * 256 + threadIdx.x;
    if (e < N_EDGES) {
        int d = eidx[N_EDGES + e];
        int slot = atomicAdd(&rowp[d], 1);
        esrc[slot] = eidx[e];
    }
}

// ---------------- encoder: h0 = relu(x @ W_enc + b) -> bf16 packed ----------------
__global__ __launch_bounds__(256) void enc_kernel(const float* __restrict__ x,
                                                  const float* __restrict__ W,
                                                  const float* __restrict__ b,
                                                  unsigned* __restrict__ h0) {
    __shared__ float Wl[16 * 128];
    int tid = threadIdx.x;
    for (int i = tid; i < 16 * 128; i += 256) Wl[i] = W[i];
    __syncthreads();
    int cp = tid & 63;      // column pair
    int rl = tid >> 6;      // 0..3
    float b0 = b[cp * 2], b1 = b[cp * 2 + 1];
    int row0 = blockIdx.x * 16;
    for (int it = 0; it < 4; it++) {
        int row = row0 + it * 4 + rl;
        if (row < N_NODES) {
            float a0 = b0, a1 = b1;
            #pragma unroll
            for (int k = 0; k < 16; k++) {
                float xv = x[row * 16 + k];
                a0 += xv * Wl[k * 128 + cp * 2];
                a1 += xv * Wl[k * 128 + cp * 2 + 1];
            }
            h0[row * 64 + cp] = pack2(fmaxf(a0, 0.0f), fmaxf(a1, 0.0f));
        }
    }
}

// ---------------- GEMM: hws[r] = dinv[r] * (h[r] @ W), bf16 in/out, f32 math ----------------
// input h: N x 128 bf16 (packed pairs). W row-major [128][NOUT] f32.
template <int NOUT>
__global__ __launch_bounds__(256) void gemm_kernel(const unsigned* __restrict__ hg,
                                                   const float* __restrict__ W,
                                                   const float* __restrict__ dinv,
                                                   unsigned short* __restrict__ outb) {
    constexpr int CT = NOUT / 4;
    constexpr int RT = 256 / CT;
    constexpr int BM = RT * 4;
    __shared__ float Wl[128 * NOUT];
    __shared__ float hs[BM * 128];
    int tid = threadIdx.x;
    for (int i = tid; i < 128 * NOUT / 4; i += 256) ((float4*)Wl)[i] = ((const float4*)W)[i];
    int row0 = blockIdx.x * BM;
    for (int p = tid; p < BM * 64; p += 256) {
        int r = p >> 6, kp = p & 63;
        int row = row0 + r;
        unsigned v = (row < N_NODES) ? hg[row * 64 + kp] : 0u;
        hs[r * 128 + kp * 2] = bf_lo(v);
        hs[r * 128 + kp * 2 + 1] = bf_hi(v);
    }
    __syncthreads();
    int c0 = (tid % CT) * 4;
    int r0 = (tid / CT) * 4;
    float acc[4][4] = {};
    for (int kb = 0; kb < 128; kb += 4) {
        float4 hv[4];
        #pragma unroll
        for (int i = 0; i < 4; i++) hv[i] = *(const float4*)&hs[(r0 + i) * 128 + kb];
        float4 wv[4];
        #pragma unroll
        for (int j = 0; j < 4; j++) wv[j] = *(const float4*)&Wl[(kb + j) * NOUT + c0];
        #pragma unroll
        for (int i = 0; i < 4; i++) {
            const float* hp = (const float*)&hv[i];
            #pragma unroll
            for (int j = 0; j < 4; j++) {
                float hk = hp[j];
                acc[i][0] += hk * wv[j].x;
                acc[i][1] += hk * wv[j].y;
                acc[i][2] += hk * wv[j].z;
                acc[i][3] += hk * wv[j].w;
            }
        }
    }
    #pragma unroll
    for (int i = 0; i < 4; i++) {
        int row = row0 + r0 + i;
        if (row < N_NODES) {
            float d = dinv[row];
            ushort4 o;
            o.x = f2bf(d * acc[i][0]);
            o.y = f2bf(d * acc[i][1]);
            o.z = f2bf(d * acc[i][2]);
            o.w = f2bf(d * acc[i][3]);
            *(ushort4*)&outb[(size_t)row * NOUT + c0] = o;
        }
    }
}

// ---------------- agg layer1 (F=128): h1 = relu(b + dinv_i * (hws[i] + sum hws[src])) -> bf16
__global__ __launch_bounds__(256) void agg128_kernel(const unsigned* __restrict__ hws,
                                                     const int* __restrict__ esrc,
                                                     const int* __restrict__ rowp_end,
                                                     const int* __restrict__ cnt,
                                                     const float* __restrict__ dinv,
                                                     const float* __restrict__ bias,
                                                     unsigned* __restrict__ h1) {
    int wave = threadIdx.x >> 6, lane = threadIdx.x & 63;
    int i = blockIdx.x * 4 + wave;
    if (i >= N_NODES) return;
    float di = dinv[i];
    int end = rowp_end[i];
    int start = end - cnt[i];
    unsigned sv = hws[i * 64 + lane];
    float a0 = bf_lo(sv), a1 = bf_hi(sv);
    int e = start;
    for (; e + 4 <= end; e += 4) {
        int s0 = esrc[e], s1 = esrc[e + 1], s2 = esrc[e + 2], s3 = esrc[e + 3];
        unsigned v0 = hws[s0 * 64 + lane];
        unsigned v1 = hws[s1 * 64 + lane];
        unsigned v2 = hws[s2 * 64 + lane];
        unsigned v3 = hws[s3 * 64 + lane];
        a0 += bf_lo(v0) + bf_lo(v1) + bf_lo(v2) + bf_lo(v3);
        a1 += bf_hi(v0) + bf_hi(v1) + bf_hi(v2) + bf_hi(v3);
    }
    for (; e < end; e++) {
        unsigned v = hws[esrc[e] * 64 + lane];
        a0 += bf_lo(v); a1 += bf_hi(v);
    }
    float o0 = bias[lane * 2] + di * a0;
    float o1 = bias[lane * 2 + 1] + di * a1;
    h1[i * 64 + lane] = pack2(fmaxf(o0, 0.0f), fmaxf(o1, 0.0f));
}

// ---------------- agg layer2 (F=64) fused with node scoring ----------------
__global__ __launch_bounds__(256) void agg64_kernel(const unsigned short* __restrict__ hws,
                                                    const int* __restrict__ esrc,
                                                    const int* __restrict__ rowp_end,
                                                    const int* __restrict__ cnt,
                                                    const float* __restrict__ dinv,
                                                    const float* __restrict__ bias,
                                                    const float* __restrict__ Wsw,
                                                    const float* __restrict__ Wv,
                                                    const float* __restrict__ bv,
                                                    float* __restrict__ aarr,
                                                    float* __restrict__ carr,
                                                    float* __restrict__ outv) {
    int wave = threadIdx.x >> 6, lane = threadIdx.x & 63;
    int i = blockIdx.x * 4 + wave;
    if (i >= N_NODES) return;
    float di = dinv[i];
    int end = rowp_end[i];
    int start = end - cnt[i];
    float acc = bf2f(hws[i * 64 + lane]);
    int e = start;
    for (; e + 4 <= end; e += 4) {
        int s0 = esrc[e], s1 = esrc[e + 1], s2 = esrc[e + 2], s3 = esrc[e + 3];
        float v0 = bf2f(hws[s0 * 64 + lane]);
        float v1 = bf2f(hws[s1 * 64 + lane]);
        float v2 = bf2f(hws[s2 * 64 + lane]);
        float v3 = bf2f(hws[s3 * 64 + lane]);
        acc += v0 + v1 + v2 + v3;
    }
    for (; e < end; e++) acc += bf2f(hws[esrc[e] * 64 + lane]);
    float h2 = bias[lane] + di * acc;
    float h = fmaxf(h2, 0.0f);
    float pa = h * Wsw[lane];
    float pc = h * Wsw[64 + lane];
    float pv = h * Wv[lane];
    #pragma unroll
    for (int m = 32; m >= 1; m >>= 1) {
        pa += __shfl_xor(pa, m, 64);
        pc += __shfl_xor(pc, m, 64);
        pv += __shfl_xor(pv, m, 64);
    }
    if (lane == 0) {
        aarr[i] = pa;
        carr[i] = pc;
        float v = 1.0f / (1.0f + expf(-(pv + bv[0])));
        float t = 0.9f + 0.2f * v;
        float vw = fminf(fmaxf(t * t, 0.81f), 1.21f);
        outv[i] = sqrtf(vw);
    }
}

// ---------------- per-edge switch scores ----------------
__global__ void edge_kernel(const int* __restrict__ eidx, const float* __restrict__ aarr,
                            const float* __restrict__ carr, const float* __restrict__ bsw,
                            float* __restrict__ out) {
    int e = blockIdx.x * 256 + threadIdx.x;
    if (e < N_EDGES) {
        int s = eidx[e], d = eidx[N_EDGES + e];
        float z = aarr[s] + carr[d] + bsw[0];
        float y = 1.0f / (1.0f + expf(-z));
        out[e] = fminf(fmaxf(y, 0.0f), 1.0f);
    }
}

extern "C" void kernel_launch(void* const* d_in, const int* in_sizes, int n_in,
                              void* d_out, int out_size, void* d_ws, size_t ws_size,
                              hipStream_t stream) {
    const float* x     = (const float*)d_in[0];
    const int*   eidx  = (const int*)d_in[1];
    const float* W_enc = (const float*)d_in[2];
    const float* b_enc = (const float*)d_in[3];
    const float* W_g0  = (const float*)d_in[4];
    const float* b_g0  = (const float*)d_in[5];
    const float* W_g1  = (const float*)d_in[6];
    const float* b_g1  = (const float*)d_in[7];
    const float* W_sw  = (const float*)d_in[8];
    const float* b_sw  = (const float*)d_in[9];
    const float* W_v   = (const float*)d_in[10];
    const float* b_v   = (const float*)d_in[11];
    float* out = (float*)d_out;

    char* ws = (char*)d_ws;
    size_t off = 0;
    auto alloc = [&](size_t bytes) {
        void* p = ws + off;
        off = (off + bytes + 255) & ~(size_t)255;
        return p;
    };
    unsigned*       h0   = (unsigned*)alloc((size_t)N_NODES * 64 * 4);        // N x 128 bf16
    unsigned short* hws1 = (unsigned short*)alloc((size_t)N_NODES * 128 * 2); // N x 128 bf16
    unsigned*       h1   = (unsigned*)alloc((size_t)N_NODES * 64 * 4);        // N x 128 bf16
    unsigned short* hws2 = (unsigned short*)alloc((size_t)N_NODES * 64 * 2);  // N x 64 bf16
    int*   cnt  = (int*)alloc((size_t)N_NODES * 4);
    int*   rowp = (int*)alloc((size_t)N_NODES * 4);
    float* dinv = (float*)alloc((size_t)N_NODES * 4);
    float* aarr = (float*)alloc((size_t)N_NODES * 4);
    float* carr = (float*)alloc((size_t)N_NODES * 4);
    int*   esrc = (int*)alloc((size_t)N_EDGES * 4);
    int*   bsum = (int*)alloc(128 * 4);

    hipMemsetAsync(cnt, 0, (size_t)N_NODES * 4, stream);
    count_kernel<<<(N_EDGES + 255) / 256, 256, 0, stream>>>(eidx, cnt);
    dinv_kernel<<<(N_NODES + 255) / 256, 256, 0, stream>>>(cnt, dinv);
    int nb = (N_NODES + 1023) / 1024;
    scan1_kernel<<<nb, 256, 0, stream>>>(cnt, rowp, bsum);
    scan2_kernel<<<1, 128, 0, stream>>>(bsum, nb);
    scan3_kernel<<<(N_NODES + 255) / 256, 256, 0, stream>>>(rowp, bsum);
    scatter_kernel<<<(N_EDGES + 255) / 256, 256, 0, stream>>>(eidx, rowp, esrc);

    enc_kernel<<<(N_NODES + 15) / 16, 256, 0, stream>>>(x, W_enc, b_enc, h0);
    gemm_kernel<128><<<(N_NODES + 31) / 32, 256, 0, stream>>>(h0, W_g0, dinv, hws1);
    agg128_kernel<<<(N_NODES + 3) / 4, 256, 0, stream>>>((const unsigned*)hws1, esrc, rowp, cnt, dinv, b_g0, h1);
    gemm_kernel<64><<<(N_NODES + 63) / 64, 256, 0, stream>>>(h1, W_g1, dinv, hws2);
    agg64_kernel<<<(N_NODES + 3) / 4, 256, 0, stream>>>(hws2, esrc, rowp, cnt, dinv, b_g1,
                                                        W_sw, W_v, b_v, aarr, carr, out + N_EDGES);
    edge_kernel<<<(N_EDGES + 255) / 256, 256, 0, stream>>>(eidx, aarr, carr, b_sw, out);
}

// Round 3
// 429.189 us; speedup vs baseline: 1.8718x; 1.3122x over previous
//
#include <hip/hip_runtime.h>
#include <math.h>

#define N_NODES 100000
#define N_EDGES 1600000
#define NB 196            // buckets of 512 nodes: (100000+511)>>9
#define CHUNK 4096
#define NBLK_E ((N_EDGES + CHUNK - 1) / CHUNK)   // 391

// ---------- bf16 helpers (packed pair in a uint: low 16 = even elem) ----------
__device__ inline float bf_lo(unsigned v) { union { unsigned u; float f; } c; c.u = v << 16; return c.f; }
__device__ inline float bf_hi(unsigned v) { union { unsigned u; float f; } c; c.u = v & 0xffff0000u; return c.f; }
__device__ inline float bf2f(unsigned short h) { union { unsigned u; float f; } c; c.u = ((unsigned)h) << 16; return c.f; }
__device__ inline unsigned short f2bf(float f) {
    union { float f; unsigned u; } c; c.f = f;
    unsigned r = c.u + 0x7fffu + ((c.u >> 16) & 1u);   // round-nearest-even
    return (unsigned short)(r >> 16);
}
__device__ inline unsigned pack2(float a, float b) {
    return (unsigned)f2bf(a) | ((unsigned)f2bf(b) << 16);
}

// ================= CSR build, bucketed =================
// A: global bucket histogram (196 atomics per block, not per edge)
__global__ __launch_bounds__(256) void hist_kernel(const int* __restrict__ eidx,
                                                   int* __restrict__ ghist) {
    __shared__ int lh[NB];
    int tid = threadIdx.x;
    for (int i = tid; i < NB; i += 256) lh[i] = 0;
    __syncthreads();
    int base = blockIdx.x * CHUNK;
    #pragma unroll
    for (int j = 0; j < CHUNK / 256; j++) {
        int e = base + j * 256 + tid;
        if (e < N_EDGES) atomicAdd(&lh[eidx[N_EDGES + e] >> 9], 1);
    }
    __syncthreads();
    for (int i = tid; i < NB; i += 256) if (lh[i]) atomicAdd(&ghist[i], lh[i]);
}

// B: exclusive scan of 196 bucket totals -> gbase[0..NB], init gcur
__global__ void scanb_kernel(const int* __restrict__ ghist, int* __restrict__ gbase,
                             int* __restrict__ gcur) {
    __shared__ int sh[256];
    int tid = threadIdx.x;
    int v = (tid < NB) ? ghist[tid] : 0;
    sh[tid] = v; __syncthreads();
    for (int off = 1; off < 256; off <<= 1) {
        int add = (tid >= off) ? sh[tid - off] : 0;
        __syncthreads();
        sh[tid] += add;
        __syncthreads();
    }
    int incl = sh[tid];
    if (tid < NB) { gbase[tid] = incl - v; gcur[tid] = incl - v; }
    if (tid == NB - 1) gbase[NB] = incl;
}

// C: partition edges into bucket-contiguous ebuf, packed (dloc<<17)|src
__global__ __launch_bounds__(256) void part_kernel(const int* __restrict__ eidx,
                                                   int* __restrict__ gcur,
                                                   unsigned* __restrict__ ebuf) {
    __shared__ int lh[NB];
    __shared__ int lbase[NB];
    int tid = threadIdx.x;
    int base = blockIdx.x * CHUNK;
    int d[CHUNK / 256], s[CHUNK / 256];
    for (int i = tid; i < NB; i += 256) lh[i] = 0;
    __syncthreads();
    #pragma unroll
    for (int j = 0; j < CHUNK / 256; j++) {
        int e = base + j * 256 + tid;
        if (e < N_EDGES) {
            d[j] = eidx[N_EDGES + e];
            s[j] = eidx[e];
            atomicAdd(&lh[d[j] >> 9], 1);
        } else d[j] = -1;
    }
    __syncthreads();
    for (int i = tid; i < NB; i += 256) {
        int c = lh[i];
        lbase[i] = c ? atomicAdd(&gcur[i], c) : 0;
    }
    __syncthreads();
    for (int i = tid; i < NB; i += 256) lh[i] = 0;
    __syncthreads();
    #pragma unroll
    for (int j = 0; j < CHUNK / 256; j++) {
        if (d[j] >= 0) {
            int b = d[j] >> 9;
            int off = lbase[b] + atomicAdd(&lh[b], 1);
            ebuf[off] = ((unsigned)(d[j] & 511) << 17) | (unsigned)s[j];
        }
    }
}

// D: per-bucket fine CSR. Block owns nodes [b*512, b*512+512) exclusively.
__global__ __launch_bounds__(256) void csr_fine_kernel(const unsigned* __restrict__ ebuf,
                                                       const int* __restrict__ gbase,
                                                       int* __restrict__ esrc,
                                                       int* __restrict__ cnt,
                                                       int* __restrict__ rowp_end,
                                                       float* __restrict__ dinv) {
    __shared__ int lcnt[512];
    __shared__ int lpre[512];   // exclusive prefix
    __shared__ int wsum[4];
    int b = blockIdx.x;
    int tid = threadIdx.x;
    int beg = gbase[b], end = gbase[b + 1];
    lcnt[tid] = 0; lcnt[tid + 256] = 0;
    __syncthreads();
    for (int e = beg + tid; e < end; e += 256) {
        unsigned v = ebuf[e];
        atomicAdd(&lcnt[v >> 17], 1);
    }
    __syncthreads();
    // scan 512 counts: thread t handles elems 2t, 2t+1
    int a0 = lcnt[2 * tid], a1 = lcnt[2 * tid + 1];
    int ps = a0 + a1;
    int lane = tid & 63, wv = tid >> 6;
    int val = ps;
    #pragma unroll
    for (int off = 1; off < 64; off <<= 1) {
        int n = __shfl_up(val, off, 64);
        if (lane >= off) val += n;
    }
    if (lane == 63) wsum[wv] = val;
    __syncthreads();
    int wbase = 0;
    for (int w = 0; w < wv; w++) wbase += wsum[w];
    int excl = wbase + val - ps;          // exclusive prefix of pair
    lpre[2 * tid] = excl;
    lpre[2 * tid + 1] = excl + a0;
    __syncthreads();
    // per-node outputs (block-exclusive contiguous range)
    int node0 = b * 512;
    for (int i = tid; i < 512; i += 256) {
        int node = node0 + i;
        if (node < N_NODES) {
            int c = lcnt[i];
            cnt[node] = c;
            rowp_end[node] = beg + lpre[i] + c;
            dinv[node] = rsqrtf(1.0f + (float)c);
        }
    }
    __syncthreads();
    lcnt[tid] = 0; lcnt[tid + 256] = 0;   // reuse as cursors
    __syncthreads();
    for (int e = beg + tid; e < end; e += 256) {
        unsigned v = ebuf[e];
        int dloc = v >> 17;
        int pos = beg + lpre[dloc] + atomicAdd(&lcnt[dloc], 1);
        esrc[pos] = (int)(v & 0x1FFFFu);
    }
}

// ---------------- encoder: h0 = relu(x @ W_enc + b) -> bf16 packed ----------------
__global__ __launch_bounds__(256) void enc_kernel(const float* __restrict__ x,
                                                  const float* __restrict__ W,
                                                  const float* __restrict__ b,
                                                  unsigned* __restrict__ h0) {
    __shared__ float Wl[16 * 128];
    int tid = threadIdx.x;
    for (int i = tid; i < 16 * 128; i += 256) Wl[i] = W[i];
    __syncthreads();
    int cp = tid & 63;      // column pair
    int rl = tid >> 6;      // 0..3
    float b0 = b[cp * 2], b1 = b[cp * 2 + 1];
    int row0 = blockIdx.x * 16;
    for (int it = 0; it < 4; it++) {
        int row = row0 + it * 4 + rl;
        if (row < N_NODES) {
            float a0 = b0, a1 = b1;
            #pragma unroll
            for (int k = 0; k < 16; k++) {
                float xv = x[row * 16 + k];
                a0 += xv * Wl[k * 128 + cp * 2];
                a1 += xv * Wl[k * 128 + cp * 2 + 1];
            }
            h0[row * 64 + cp] = pack2(fmaxf(a0, 0.0f), fmaxf(a1, 0.0f));
        }
    }
}

// ---------------- GEMM: hws[r] = dinv[r] * (h[r] @ W), bf16 in/out, f32 math ----------------
template <int NOUT>
__global__ __launch_bounds__(256) void gemm_kernel(const unsigned* __restrict__ hg,
                                                   const float* __restrict__ W,
                                                   const float* __restrict__ dinv,
                                                   unsigned short* __restrict__ outb) {
    constexpr int CT = NOUT / 4;
    constexpr int RT = 256 / CT;
    constexpr int BM = RT * 4;
    __shared__ float Wl[128 * NOUT];
    __shared__ float hs[BM * 128];
    int tid = threadIdx.x;
    for (int i = tid; i < 128 * NOUT / 4; i += 256) ((float4*)Wl)[i] = ((const float4*)W)[i];
    int row0 = blockIdx.x * BM;
    for (int p = tid; p < BM * 64; p += 256) {
        int r = p >> 6, kp = p & 63;
        int row = row0 + r;
        unsigned v = (row < N_NODES) ? hg[row * 64 + kp] : 0u;
        hs[r * 128 + kp * 2] = bf_lo(v);
        hs[r * 128 + kp * 2 + 1] = bf_hi(v);
    }
    __syncthreads();
    int c0 = (tid % CT) * 4;
    int r0 = (tid / CT) * 4;
    float acc[4][4] = {};
    for (int kb = 0; kb < 128; kb += 4) {
        float4 hv[4];
        #pragma unroll
        for (int i = 0; i < 4; i++) hv[i] = *(const float4*)&hs[(r0 + i) * 128 + kb];
        float4 wv[4];
        #pragma unroll
        for (int j = 0; j < 4; j++) wv[j] = *(const float4*)&Wl[(kb + j) * NOUT + c0];
        #pragma unroll
        for (int i = 0; i < 4; i++) {
            const float* hp = (const float*)&hv[i];
            #pragma unroll
            for (int j = 0; j < 4; j++) {
                float hk = hp[j];
                acc[i][0] += hk * wv[j].x;
                acc[i][1] += hk * wv[j].y;
                acc[i][2] += hk * wv[j].z;
                acc[i][3] += hk * wv[j].w;
            }
        }
    }
    #pragma unroll
    for (int i = 0; i < 4; i++) {
        int row = row0 + r0 + i;
        if (row < N_NODES) {
            float d = dinv[row];
            ushort4 o;
            o.x = f2bf(d * acc[i][0]);
            o.y = f2bf(d * acc[i][1]);
            o.z = f2bf(d * acc[i][2]);
            o.w = f2bf(d * acc[i][3]);
            *(ushort4*)&outb[(size_t)row * NOUT + c0] = o;
        }
    }
}

// ---------------- agg layer1 (F=128): h1 = relu(b + dinv_i * (hws[i] + sum hws[src])) -> bf16
__global__ __launch_bounds__(256) void agg128_kernel(const unsigned* __restrict__ hws,
                                                     const int* __restrict__ esrc,
                                                     const int* __restrict__ rowp_end,
                                                     const int* __restrict__ cnt,
                                                     const float* __restrict__ dinv,
                                                     const float* __restrict__ bias,
                                                     unsigned* __restrict__ h1) {
    int wave = threadIdx.x >> 6, lane = threadIdx.x & 63;
    int i = blockIdx.x * 4 + wave;
    if (i >= N_NODES) return;
    float di = dinv[i];
    int end = rowp_end[i];
    int start = end - cnt[i];
    unsigned sv = hws[i * 64 + lane];
    float a0 = bf_lo(sv), a1 = bf_hi(sv);
    int e = start;
    for (; e + 4 <= end; e += 4) {
        int s0 = esrc[e], s1 = esrc[e + 1], s2 = esrc[e + 2], s3 = esrc[e + 3];
        unsigned v0 = hws[s0 * 64 + lane];
        unsigned v1 = hws[s1 * 64 + lane];
        unsigned v2 = hws[s2 * 64 + lane];
        unsigned v3 = hws[s3 * 64 + lane];
        a0 += bf_lo(v0) + bf_lo(v1) + bf_lo(v2) + bf_lo(v3);
        a1 += bf_hi(v0) + bf_hi(v1) + bf_hi(v2) + bf_hi(v3);
    }
    for (; e < end; e++) {
        unsigned v = hws[esrc[e] * 64 + lane];
        a0 += bf_lo(v); a1 += bf_hi(v);
    }
    float o0 = bias[lane * 2] + di * a0;
    float o1 = bias[lane * 2 + 1] + di * a1;
    h1[i * 64 + lane] = pack2(fmaxf(o0, 0.0f), fmaxf(o1, 0.0f));
}

// ---------------- agg layer2 (F=64) fused with node scoring ----------------
__global__ __launch_bounds__(256) void agg64_kernel(const unsigned short* __restrict__ hws,
                                                    const int* __restrict__ esrc,
                                                    const int* __restrict__ rowp_end,
                                                    const int* __restrict__ cnt,
                                                    const float* __restrict__ dinv,
                                                    const float* __restrict__ bias,
                                                    const float* __restrict__ Wsw,
                                                    const float* __restrict__ Wv,
                                                    const float* __restrict__ bv,
                                                    float* __restrict__ aarr,
                                                    float* __restrict__ carr,
                                                    float* __restrict__ outv) {
    int wave = threadIdx.x >> 6, lane = threadIdx.x & 63;
    int i = blockIdx.x * 4 + wave;
    if (i >= N_NODES) return;
    float di = dinv[i];
    int end = rowp_end[i];
    int start = end - cnt[i];
    float acc = bf2f(hws[i * 64 + lane]);
    int e = start;
    for (; e + 4 <= end; e += 4) {
        int s0 = esrc[e], s1 = esrc[e + 1], s2 = esrc[e + 2], s3 = esrc[e + 3];
        float v0 = bf2f(hws[s0 * 64 + lane]);
        float v1 = bf2f(hws[s1 * 64 + lane]);
        float v2 = bf2f(hws[s2 * 64 + lane]);
        float v3 = bf2f(hws[s3 * 64 + lane]);
        acc += v0 + v1 + v2 + v3;
    }
    for (; e < end; e++) acc += bf2f(hws[esrc[e] * 64 + lane]);
    float h2 = bias[lane] + di * acc;
    float h = fmaxf(h2, 0.0f);
    float pa = h * Wsw[lane];
    float pc = h * Wsw[64 + lane];
    float pv = h * Wv[lane];
    #pragma unroll
    for (int m = 32; m >= 1; m >>= 1) {
        pa += __shfl_xor(pa, m, 64);
        pc += __shfl_xor(pc, m, 64);
        pv += __shfl_xor(pv, m, 64);
    }
    if (lane == 0) {
        aarr[i] = pa;
        carr[i] = pc;
        float v = 1.0f / (1.0f + expf(-(pv + bv[0])));
        float t = 0.9f + 0.2f * v;
        float vw = fminf(fmaxf(t * t, 0.81f), 1.21f);
        outv[i] = sqrtf(vw);
    }
}

// ---------------- per-edge switch scores ----------------
__global__ void edge_kernel(const int* __restrict__ eidx, const float* __restrict__ aarr,
                            const float* __restrict__ carr, const float* __restrict__ bsw,
                            float* __restrict__ out) {
    int e = blockIdx.x * 256 + threadIdx.x;
    if (e < N_EDGES) {
        int s = eidx[e], d = eidx[N_EDGES + e];
        float z = aarr[s] + carr[d] + bsw[0];
        float y = 1.0f / (1.0f + expf(-z));
        out[e] = fminf(fmaxf(y, 0.0f), 1.0f);
    }
}

extern "C" void kernel_launch(void* const* d_in, const int* in_sizes, int n_in,
                              void* d_out, int out_size, void* d_ws, size_t ws_size,
                              hipStream_t stream) {
    const float* x     = (const float*)d_in[0];
    const int*   eidx  = (const int*)d_in[1];
    const float* W_enc = (const float*)d_in[2];
    const float* b_enc = (const float*)d_in[3];
    const float* W_g0  = (const float*)d_in[4];
    const float* b_g0  = (const float*)d_in[5];
    const float* W_g1  = (const float*)d_in[6];
    const float* b_g1  = (const float*)d_in[7];
    const float* W_sw  = (const float*)d_in[8];
    const float* b_sw  = (const float*)d_in[9];
    const float* W_v   = (const float*)d_in[10];
    const float* b_v   = (const float*)d_in[11];
    float* out = (float*)d_out;

    char* ws = (char*)d_ws;
    size_t off = 0;
    auto alloc = [&](size_t bytes) {
        void* p = ws + off;
        off = (off + bytes + 255) & ~(size_t)255;
        return p;
    };
    unsigned*       h0   = (unsigned*)alloc((size_t)N_NODES * 64 * 4);        // N x 128 bf16
    unsigned short* hws1 = (unsigned short*)alloc((size_t)N_NODES * 128 * 2); // N x 128 bf16
    unsigned*       h1   = (unsigned*)alloc((size_t)N_NODES * 64 * 4);        // N x 128 bf16
    unsigned short* hws2 = (unsigned short*)alloc((size_t)N_NODES * 64 * 2);  // N x 64 bf16
    int*   cnt  = (int*)alloc((size_t)N_NODES * 4);
    int*   rowp = (int*)alloc((size_t)N_NODES * 4);
    float* dinv = (float*)alloc((size_t)N_NODES * 4);
    float* aarr = (float*)alloc((size_t)N_NODES * 4);
    float* carr = (float*)alloc((size_t)N_NODES * 4);
    int*   esrc = (int*)alloc((size_t)N_EDGES * 4);
    unsigned* ebuf = (unsigned*)alloc((size_t)N_EDGES * 4);
    int*   ghist = (int*)alloc(256 * 4);
    int*   gbase = (int*)alloc(256 * 4);
    int*   gcur  = (int*)alloc(256 * 4);

    hipMemsetAsync(ghist, 0, NB * 4, stream);
    hist_kernel<<<NBLK_E, 256, 0, stream>>>(eidx, ghist);
    scanb_kernel<<<1, 256, 0, stream>>>(ghist, gbase, gcur);
    part_kernel<<<NBLK_E, 256, 0, stream>>>(eidx, gcur, ebuf);
    csr_fine_kernel<<<NB, 256, 0, stream>>>(ebuf, gbase, esrc, cnt, rowp, dinv);

    enc_kernel<<<(N_NODES + 15) / 16, 256, 0, stream>>>(x, W_enc, b_enc, h0);
    gemm_kernel<128><<<(N_NODES + 31) / 32, 256, 0, stream>>>(h0, W_g0, dinv, hws1);
    agg128_kernel<<<(N_NODES + 3) / 4, 256, 0, stream>>>((const unsigned*)hws1, esrc, rowp, cnt, dinv, b_g0, h1);
    gemm_kernel<64><<<(N_NODES + 63) / 64, 256, 0, stream>>>(h1, W_g1, dinv, hws2);
    agg64_kernel<<<(N_NODES + 3) / 4, 256, 0, stream>>>(hws2, esrc, rowp, cnt, dinv, b_g1,
                                                        W_sw, W_v, b_v, aarr, carr, out + N_EDGES);
    edge_kernel<<<(N_EDGES + 255) / 256, 256, 0, stream>>>(eidx, aarr, carr, b_sw, out);
}

// Round 4
// 342.169 us; speedup vs baseline: 2.3478x; 1.2543x over previous
//
#include <hip/hip_runtime.h>
#include <math.h>

#define N_NODES 100000
#define N_EDGES 1600000
#define NB 196            // buckets of 512 nodes: (100000+511)>>9
#define CHUNK 4096
#define NBLK_E ((N_EDGES + CHUNK - 1) / CHUNK)   // 391

typedef __attribute__((ext_vector_type(8))) short bf16x8;
typedef __attribute__((ext_vector_type(4))) float f32x4;

// ---------- bf16 helpers (packed pair in a uint: low 16 = even elem) ----------
__device__ inline float bf_lo(unsigned v) { union { unsigned u; float f; } c; c.u = v << 16; return c.f; }
__device__ inline float bf_hi(unsigned v) { union { unsigned u; float f; } c; c.u = v & 0xffff0000u; return c.f; }
__device__ inline float bf2f(unsigned short h) { union { unsigned u; float f; } c; c.u = ((unsigned)h) << 16; return c.f; }
__device__ inline unsigned short f2bf(float f) {
    union { float f; unsigned u; } c; c.f = f;
    unsigned r = c.u + 0x7fffu + ((c.u >> 16) & 1u);   // round-nearest-even
    return (unsigned short)(r >> 16);
}
__device__ inline unsigned pack2(float a, float b) {
    return (unsigned)f2bf(a) | ((unsigned)f2bf(b) << 16);
}

// ================= CSR build, bucketed =================
__global__ __launch_bounds__(256) void hist_kernel(const int* __restrict__ eidx,
                                                   int* __restrict__ ghist) {
    __shared__ int lh[NB];
    int tid = threadIdx.x;
    for (int i = tid; i < NB; i += 256) lh[i] = 0;
    __syncthreads();
    int base = blockIdx.x * CHUNK;
    #pragma unroll
    for (int j = 0; j < CHUNK / 256; j++) {
        int e = base + j * 256 + tid;
        if (e < N_EDGES) atomicAdd(&lh[eidx[N_EDGES + e] >> 9], 1);
    }
    __syncthreads();
    for (int i = tid; i < NB; i += 256) if (lh[i]) atomicAdd(&ghist[i], lh[i]);
}

__global__ void scanb_kernel(const int* __restrict__ ghist, int* __restrict__ gbase,
                             int* __restrict__ gcur) {
    __shared__ int sh[256];
    int tid = threadIdx.x;
    int v = (tid < NB) ? ghist[tid] : 0;
    sh[tid] = v; __syncthreads();
    for (int off = 1; off < 256; off <<= 1) {
        int add = (tid >= off) ? sh[tid - off] : 0;
        __syncthreads();
        sh[tid] += add;
        __syncthreads();
    }
    int incl = sh[tid];
    if (tid < NB) { gbase[tid] = incl - v; gcur[tid] = incl - v; }
    if (tid == NB - 1) gbase[NB] = incl;
}

__global__ __launch_bounds__(256) void part_kernel(const int* __restrict__ eidx,
                                                   int* __restrict__ gcur,
                                                   unsigned* __restrict__ ebuf) {
    __shared__ int lh[NB];
    __shared__ int lbase[NB];
    int tid = threadIdx.x;
    int base = blockIdx.x * CHUNK;
    int d[CHUNK / 256], s[CHUNK / 256];
    for (int i = tid; i < NB; i += 256) lh[i] = 0;
    __syncthreads();
    #pragma unroll
    for (int j = 0; j < CHUNK / 256; j++) {
        int e = base + j * 256 + tid;
        if (e < N_EDGES) {
            d[j] = eidx[N_EDGES + e];
            s[j] = eidx[e];
            atomicAdd(&lh[d[j] >> 9], 1);
        } else d[j] = -1;
    }
    __syncthreads();
    for (int i = tid; i < NB; i += 256) {
        int c = lh[i];
        lbase[i] = c ? atomicAdd(&gcur[i], c) : 0;
    }
    __syncthreads();
    for (int i = tid; i < NB; i += 256) lh[i] = 0;
    __syncthreads();
    #pragma unroll
    for (int j = 0; j < CHUNK / 256; j++) {
        if (d[j] >= 0) {
            int b = d[j] >> 9;
            int off = lbase[b] + atomicAdd(&lh[b], 1);
            ebuf[off] = ((unsigned)(d[j] & 511) << 17) | (unsigned)s[j];
        }
    }
}

__global__ __launch_bounds__(256) void csr_fine_kernel(const unsigned* __restrict__ ebuf,
                                                       const int* __restrict__ gbase,
                                                       int* __restrict__ esrc,
                                                       int* __restrict__ cnt,
                                                       int* __restrict__ rowp_end,
                                                       float* __restrict__ dinv) {
    __shared__ int lcnt[512];
    __shared__ int lpre[512];
    __shared__ int wsum[4];
    int b = blockIdx.x;
    int tid = threadIdx.x;
    int beg = gbase[b], end = gbase[b + 1];
    lcnt[tid] = 0; lcnt[tid + 256] = 0;
    __syncthreads();
    for (int e = beg + tid; e < end; e += 256) {
        unsigned v = ebuf[e];
        atomicAdd(&lcnt[v >> 17], 1);
    }
    __syncthreads();
    int a0 = lcnt[2 * tid], a1 = lcnt[2 * tid + 1];
    int ps = a0 + a1;
    int lane = tid & 63, wv = tid >> 6;
    int val = ps;
    #pragma unroll
    for (int off = 1; off < 64; off <<= 1) {
        int n = __shfl_up(val, off, 64);
        if (lane >= off) val += n;
    }
    if (lane == 63) wsum[wv] = val;
    __syncthreads();
    int wbase = 0;
    for (int w = 0; w < wv; w++) wbase += wsum[w];
    int excl = wbase + val - ps;
    lpre[2 * tid] = excl;
    lpre[2 * tid + 1] = excl + a0;
    __syncthreads();
    int node0 = b * 512;
    for (int i = tid; i < 512; i += 256) {
        int node = node0 + i;
        if (node < N_NODES) {
            int c = lcnt[i];
            cnt[node] = c;
            rowp_end[node] = beg + lpre[i] + c;
            dinv[node] = rsqrtf(1.0f + (float)c);
        }
    }
    __syncthreads();
    lcnt[tid] = 0; lcnt[tid + 256] = 0;
    __syncthreads();
    for (int e = beg + tid; e < end; e += 256) {
        unsigned v = ebuf[e];
        int dloc = v >> 17;
        int pos = beg + lpre[dloc] + atomicAdd(&lcnt[dloc], 1);
        esrc[pos] = (int)(v & 0x1FFFFu);
    }
}

// ---------------- weight convert: f32 [K][N] -> bf16 col-major [N][K] ----------------
__global__ void wconv_kernel(const float* __restrict__ Wg0, const float* __restrict__ Wg1,
                             unsigned short* __restrict__ w0t, unsigned short* __restrict__ w1t) {
    int idx = blockIdx.x * 256 + threadIdx.x;
    if (idx < 128 * 128) {
        int n = idx >> 7, k = idx & 127;
        w0t[n * 128 + k] = f2bf(Wg0[k * 128 + n]);
    } else if (idx < 128 * 128 + 64 * 128) {
        int j = idx - 128 * 128;
        int n = j >> 7, k = j & 127;
        w1t[n * 128 + k] = f2bf(Wg1[k * 64 + n]);
    }
}

// ---------------- encoder: h0 = relu(x @ W_enc + b) -> bf16 packed ----------------
__global__ __launch_bounds__(256) void enc_kernel(const float* __restrict__ x,
                                                  const float* __restrict__ W,
                                                  const float* __restrict__ b,
                                                  unsigned* __restrict__ h0) {
    __shared__ float Wl[16 * 128];
    int tid = threadIdx.x;
    for (int i = tid; i < 16 * 128; i += 256) Wl[i] = W[i];
    __syncthreads();
    int cp = tid & 63;
    int rl = tid >> 6;
    float b0 = b[cp * 2], b1 = b[cp * 2 + 1];
    int row0 = blockIdx.x * 16;
    for (int it = 0; it < 4; it++) {
        int row = row0 + it * 4 + rl;
        if (row < N_NODES) {
            float a0 = b0, a1 = b1;
            #pragma unroll
            for (int k = 0; k < 16; k++) {
                float xv = x[row * 16 + k];
                a0 += xv * Wl[k * 128 + cp * 2];
                a1 += xv * Wl[k * 128 + cp * 2 + 1];
            }
            h0[row * 64 + cp] = pack2(fmaxf(a0, 0.0f), fmaxf(a1, 0.0f));
        }
    }
}

// ---------------- MFMA GEMM: outb[r] = dinv[r]*(h[r] @ W), h bf16 [N][128], Wt bf16 col-major
template <int NOUT>
__global__ __launch_bounds__(256) void mfma_gemm_kernel(const unsigned short* __restrict__ hg,
                                                        const unsigned short* __restrict__ Wt,
                                                        const float* __restrict__ dinv,
                                                        unsigned short* __restrict__ outb) {
    constexpr int PAD = 136;                      // ushorts per LDS row (+16B pad)
    __shared__ unsigned short Wl[NOUT * PAD];
    int tid = threadIdx.x;
    for (int i = tid; i < NOUT * 16; i += 256) {  // 16-byte chunks
        int n = i >> 4, c = i & 15;
        *(float4*)&Wl[n * PAD + c * 8] = *(const float4*)&Wt[n * 128 + c * 8];
    }
    int wave = tid >> 6, lane = tid & 63;
    int m = lane & 15, quad = lane >> 4;
    int row0 = blockIdx.x * 64 + wave * 16;
    int arow = row0 + m;
    bool avalid = arow < N_NODES;
    f32x4 acc[NOUT / 16];
    #pragma unroll
    for (int t = 0; t < NOUT / 16; t++) acc[t] = (f32x4){0.f, 0.f, 0.f, 0.f};
    __syncthreads();
    #pragma unroll
    for (int kc = 0; kc < 4; kc++) {
        bf16x8 af;
        if (avalid) af = *(const bf16x8*)&hg[(size_t)arow * 128 + kc * 32 + quad * 8];
        else af = (bf16x8){0, 0, 0, 0, 0, 0, 0, 0};
        #pragma unroll
        for (int t = 0; t < NOUT / 16; t++) {
            bf16x8 bf = *(const bf16x8*)&Wl[(t * 16 + m) * PAD + kc * 32 + quad * 8];
            acc[t] = __builtin_amdgcn_mfma_f32_16x16x32_bf16(af, bf, acc[t], 0, 0, 0);
        }
    }
    #pragma unroll
    for (int r = 0; r < 4; r++) {
        int row = row0 + quad * 4 + r;
        if (row < N_NODES) {
            float d = dinv[row];
            #pragma unroll
            for (int t = 0; t < NOUT / 16; t++) {
                outb[(size_t)row * NOUT + t * 16 + m] = f2bf(d * acc[t][r]);
            }
        }
    }
}

// ---------------- agg layer1 (F=128): h1 = relu(b + dinv_i * (hws[i] + sum hws[src])) -> bf16
__global__ __launch_bounds__(256) void agg128_kernel(const unsigned* __restrict__ hws,
                                                     const int* __restrict__ esrc,
                                                     const int* __restrict__ rowp_end,
                                                     const int* __restrict__ cnt,
                                                     const float* __restrict__ dinv,
                                                     const float* __restrict__ bias,
                                                     unsigned* __restrict__ h1) {
    int wave = threadIdx.x >> 6, lane = threadIdx.x & 63;
    int i = blockIdx.x * 4 + wave;
    if (i >= N_NODES) return;
    float di = dinv[i];
    int end = rowp_end[i];
    int start = end - cnt[i];
    unsigned sv = hws[i * 64 + lane];
    float a0 = bf_lo(sv), a1 = bf_hi(sv);
    int e = start;
    for (; e + 4 <= end; e += 4) {
        int s0 = esrc[e], s1 = esrc[e + 1], s2 = esrc[e + 2], s3 = esrc[e + 3];
        unsigned v0 = hws[s0 * 64 + lane];
        unsigned v1 = hws[s1 * 64 + lane];
        unsigned v2 = hws[s2 * 64 + lane];
        unsigned v3 = hws[s3 * 64 + lane];
        a0 += bf_lo(v0) + bf_lo(v1) + bf_lo(v2) + bf_lo(v3);
        a1 += bf_hi(v0) + bf_hi(v1) + bf_hi(v2) + bf_hi(v3);
    }
    for (; e < end; e++) {
        unsigned v = hws[esrc[e] * 64 + lane];
        a0 += bf_lo(v); a1 += bf_hi(v);
    }
    float o0 = bias[lane * 2] + di * a0;
    float o1 = bias[lane * 2 + 1] + di * a1;
    h1[i * 64 + lane] = pack2(fmaxf(o0, 0.0f), fmaxf(o1, 0.0f));
}

// ---------------- agg layer2 (F=64) fused with node scoring ----------------
__global__ __launch_bounds__(256) void agg64_kernel(const unsigned short* __restrict__ hws,
                                                    const int* __restrict__ esrc,
                                                    const int* __restrict__ rowp_end,
                                                    const int* __restrict__ cnt,
                                                    const float* __restrict__ dinv,
                                                    const float* __restrict__ bias,
                                                    const float* __restrict__ Wsw,
                                                    const float* __restrict__ Wv,
                                                    const float* __restrict__ bv,
                                                    float* __restrict__ aarr,
                                                    float* __restrict__ carr,
                                                    float* __restrict__ outv) {
    int wave = threadIdx.x >> 6, lane = threadIdx.x & 63;
    int i = blockIdx.x * 4 + wave;
    if (i >= N_NODES) return;
    float di = dinv[i];
    int end = rowp_end[i];
    int start = end - cnt[i];
    float acc = bf2f(hws[i * 64 + lane]);
    int e = start;
    for (; e + 4 <= end; e += 4) {
        int s0 = esrc[e], s1 = esrc[e + 1], s2 = esrc[e + 2], s3 = esrc[e + 3];
        float v0 = bf2f(hws[s0 * 64 + lane]);
        float v1 = bf2f(hws[s1 * 64 + lane]);
        float v2 = bf2f(hws[s2 * 64 + lane]);
        float v3 = bf2f(hws[s3 * 64 + lane]);
        acc += v0 + v1 + v2 + v3;
    }
    for (; e < end; e++) acc += bf2f(hws[esrc[e] * 64 + lane]);
    float h2 = bias[lane] + di * acc;
    float h = fmaxf(h2, 0.0f);
    float pa = h * Wsw[lane];
    float pc = h * Wsw[64 + lane];
    float pv = h * Wv[lane];
    #pragma unroll
    for (int m = 32; m >= 1; m >>= 1) {
        pa += __shfl_xor(pa, m, 64);
        pc += __shfl_xor(pc, m, 64);
        pv += __shfl_xor(pv, m, 64);
    }
    if (lane == 0) {
        aarr[i] = pa;
        carr[i] = pc;
        float v = 1.0f / (1.0f + expf(-(pv + bv[0])));
        float t = 0.9f + 0.2f * v;
        float vw = fminf(fmaxf(t * t, 0.81f), 1.21f);
        outv[i] = sqrtf(vw);
    }
}

// ---------------- per-edge switch scores ----------------
__global__ void edge_kernel(const int* __restrict__ eidx, const float* __restrict__ aarr,
                            const float* __restrict__ carr, const float* __restrict__ bsw,
                            float* __restrict__ out) {
    int e = blockIdx.x * 256 + threadIdx.x;
    if (e < N_EDGES) {
        int s = eidx[e], d = eidx[N_EDGES + e];
        float z = aarr[s] + carr[d] + bsw[0];
        float y = 1.0f / (1.0f + expf(-z));
        out[e] = fminf(fmaxf(y, 0.0f), 1.0f);
    }
}

extern "C" void kernel_launch(void* const* d_in, const int* in_sizes, int n_in,
                              void* d_out, int out_size, void* d_ws, size_t ws_size,
                              hipStream_t stream) {
    const float* x     = (const float*)d_in[0];
    const int*   eidx  = (const int*)d_in[1];
    const float* W_enc = (const float*)d_in[2];
    const float* b_enc = (const float*)d_in[3];
    const float* W_g0  = (const float*)d_in[4];
    const float* b_g0  = (const float*)d_in[5];
    const float* W_g1  = (const float*)d_in[6];
    const float* b_g1  = (const float*)d_in[7];
    const float* W_sw  = (const float*)d_in[8];
    const float* b_sw  = (const float*)d_in[9];
    const float* W_v   = (const float*)d_in[10];
    const float* b_v   = (const float*)d_in[11];
    float* out = (float*)d_out;

    char* ws = (char*)d_ws;
    size_t off = 0;
    auto alloc = [&](size_t bytes) {
        void* p = ws + off;
        off = (off + bytes + 255) & ~(size_t)255;
        return p;
    };
    unsigned*       h0   = (unsigned*)alloc((size_t)N_NODES * 64 * 4);        // N x 128 bf16
    unsigned short* hws1 = (unsigned short*)alloc((size_t)N_NODES * 128 * 2); // N x 128 bf16
    unsigned*       h1   = (unsigned*)alloc((size_t)N_NODES * 64 * 4);        // N x 128 bf16
    unsigned short* hws2 = (unsigned short*)alloc((size_t)N_NODES * 64 * 2);  // N x 64 bf16
    int*   cnt  = (int*)alloc((size_t)N_NODES * 4);
    int*   rowp = (int*)alloc((size_t)N_NODES * 4);
    float* dinv = (float*)alloc((size_t)N_NODES * 4);
    float* aarr = (float*)alloc((size_t)N_NODES * 4);
    float* carr = (float*)alloc((size_t)N_NODES * 4);
    int*   esrc = (int*)alloc((size_t)N_EDGES * 4);
    unsigned* ebuf = (unsigned*)alloc((size_t)N_EDGES * 4);
    int*   ghist = (int*)alloc(256 * 4);
    int*   gbase = (int*)alloc(256 * 4);
    int*   gcur  = (int*)alloc(256 * 4);
    unsigned short* w0t = (unsigned short*)alloc(128 * 128 * 2);
    unsigned short* w1t = (unsigned short*)alloc(64 * 128 * 2);

    hipMemsetAsync(ghist, 0, NB * 4, stream);
    hist_kernel<<<NBLK_E, 256, 0, stream>>>(eidx, ghist);
    scanb_kernel<<<1, 256, 0, stream>>>(ghist, gbase, gcur);
    part_kernel<<<NBLK_E, 256, 0, stream>>>(eidx, gcur, ebuf);
    csr_fine_kernel<<<NB, 256, 0, stream>>>(ebuf, gbase, esrc, cnt, rowp, dinv);

    wconv_kernel<<<96, 256, 0, stream>>>(W_g0, W_g1, w0t, w1t);
    enc_kernel<<<(N_NODES + 15) / 16, 256, 0, stream>>>(x, W_enc, b_enc, h0);
    mfma_gemm_kernel<128><<<(N_NODES + 63) / 64, 256, 0, stream>>>((const unsigned short*)h0, w0t, dinv, hws1);
    agg128_kernel<<<(N_NODES + 3) / 4, 256, 0, stream>>>((const unsigned*)hws1, esrc, rowp, cnt, dinv, b_g0, h1);
    mfma_gemm_kernel<64><<<(N_NODES + 63) / 64, 256, 0, stream>>>((const unsigned short*)h1, w1t, dinv, hws2);
    agg64_kernel<<<(N_NODES + 3) / 4, 256, 0, stream>>>(hws2, esrc, rowp, cnt, dinv, b_g1,
                                                        W_sw, W_v, b_v, aarr, carr, out + N_EDGES);
    edge_kernel<<<(N_EDGES + 255) / 256, 256, 0, stream>>>(eidx, aarr, carr, b_sw, out);
}

// Round 5
// 322.805 us; speedup vs baseline: 2.4886x; 1.0600x over previous
//
#include <hip/hip_runtime.h>
#include <math.h>

#define N_NODES 100000
#define N_EDGES 1600000
#define NB 196            // buckets of 512 nodes: (100000+511)>>9
#define CHUNK 4096
#define NBLK_E ((N_EDGES + CHUNK - 1) / CHUNK)   // 391

typedef __attribute__((ext_vector_type(8))) short bf16x8;
typedef __attribute__((ext_vector_type(4))) float f32x4;

// ---------- bf16 helpers (packed pair in a uint: low 16 = even elem) ----------
__device__ inline float bf_lo(unsigned v) { union { unsigned u; float f; } c; c.u = v << 16; return c.f; }
__device__ inline float bf_hi(unsigned v) { union { unsigned u; float f; } c; c.u = v & 0xffff0000u; return c.f; }
__device__ inline float bf2f(unsigned short h) { union { unsigned u; float f; } c; c.u = ((unsigned)h) << 16; return c.f; }
__device__ inline unsigned short f2bf(float f) {
    union { float f; unsigned u; } c; c.f = f;
    unsigned r = c.u + 0x7fffu + ((c.u >> 16) & 1u);   // round-nearest-even
    return (unsigned short)(r >> 16);
}
__device__ inline unsigned pack2(float a, float b) {
    return (unsigned)f2bf(a) | ((unsigned)f2bf(b) << 16);
}

// ================= CSR build, bucketed =================
__global__ __launch_bounds__(256) void hist_kernel(const int* __restrict__ eidx,
                                                   int* __restrict__ ghist) {
    __shared__ int lh[NB];
    int tid = threadIdx.x;
    for (int i = tid; i < NB; i += 256) lh[i] = 0;
    __syncthreads();
    int base = blockIdx.x * CHUNK;
    #pragma unroll
    for (int j = 0; j < CHUNK / 256; j++) {
        int e = base + j * 256 + tid;
        if (e < N_EDGES) atomicAdd(&lh[eidx[N_EDGES + e] >> 9], 1);
    }
    __syncthreads();
    for (int i = tid; i < NB; i += 256) if (lh[i]) atomicAdd(&ghist[i], lh[i]);
}

__global__ void scanb_kernel(const int* __restrict__ ghist, int* __restrict__ gbase,
                             int* __restrict__ gcur) {
    __shared__ int sh[256];
    int tid = threadIdx.x;
    int v = (tid < NB) ? ghist[tid] : 0;
    sh[tid] = v; __syncthreads();
    for (int off = 1; off < 256; off <<= 1) {
        int add = (tid >= off) ? sh[tid - off] : 0;
        __syncthreads();
        sh[tid] += add;
        __syncthreads();
    }
    int incl = sh[tid];
    if (tid < NB) { gbase[tid] = incl - v; gcur[tid] = incl - v; }
    if (tid == NB - 1) gbase[NB] = incl;
}

__global__ __launch_bounds__(256) void part_kernel(const int* __restrict__ eidx,
                                                   int* __restrict__ gcur,
                                                   unsigned* __restrict__ ebuf) {
    __shared__ int lh[NB];
    __shared__ int lbase[NB];
    int tid = threadIdx.x;
    int base = blockIdx.x * CHUNK;
    int d[CHUNK / 256], s[CHUNK / 256];
    for (int i = tid; i < NB; i += 256) lh[i] = 0;
    __syncthreads();
    #pragma unroll
    for (int j = 0; j < CHUNK / 256; j++) {
        int e = base + j * 256 + tid;
        if (e < N_EDGES) {
            d[j] = eidx[N_EDGES + e];
            s[j] = eidx[e];
            atomicAdd(&lh[d[j] >> 9], 1);
        } else d[j] = -1;
    }
    __syncthreads();
    for (int i = tid; i < NB; i += 256) {
        int c = lh[i];
        lbase[i] = c ? atomicAdd(&gcur[i], c) : 0;
    }
    __syncthreads();
    for (int i = tid; i < NB; i += 256) lh[i] = 0;
    __syncthreads();
    #pragma unroll
    for (int j = 0; j < CHUNK / 256; j++) {
        if (d[j] >= 0) {
            int b = d[j] >> 9;
            int off = lbase[b] + atomicAdd(&lh[b], 1);
            ebuf[off] = ((unsigned)(d[j] & 511) << 17) | (unsigned)s[j];
        }
    }
}

__global__ __launch_bounds__(256) void csr_fine_kernel(const unsigned* __restrict__ ebuf,
                                                       const int* __restrict__ gbase,
                                                       int* __restrict__ esrc,
                                                       int* __restrict__ cnt,
                                                       int* __restrict__ rowp_end,
                                                       float* __restrict__ dinv) {
    __shared__ int lcnt[512];
    __shared__ int lpre[512];
    __shared__ int wsum[4];
    int b = blockIdx.x;
    int tid = threadIdx.x;
    int beg = gbase[b], end = gbase[b + 1];
    lcnt[tid] = 0; lcnt[tid + 256] = 0;
    __syncthreads();
    for (int e = beg + tid; e < end; e += 256) {
        unsigned v = ebuf[e];
        atomicAdd(&lcnt[v >> 17], 1);
    }
    __syncthreads();
    int a0 = lcnt[2 * tid], a1 = lcnt[2 * tid + 1];
    int ps = a0 + a1;
    int lane = tid & 63, wv = tid >> 6;
    int val = ps;
    #pragma unroll
    for (int off = 1; off < 64; off <<= 1) {
        int n = __shfl_up(val, off, 64);
        if (lane >= off) val += n;
    }
    if (lane == 63) wsum[wv] = val;
    __syncthreads();
    int wbase = 0;
    for (int w = 0; w < wv; w++) wbase += wsum[w];
    int excl = wbase + val - ps;
    lpre[2 * tid] = excl;
    lpre[2 * tid + 1] = excl + a0;
    __syncthreads();
    int node0 = b * 512;
    for (int i = tid; i < 512; i += 256) {
        int node = node0 + i;
        if (node < N_NODES) {
            int c = lcnt[i];
            cnt[node] = c;
            rowp_end[node] = beg + lpre[i] + c;
            dinv[node] = rsqrtf(1.0f + (float)c);
        }
    }
    __syncthreads();
    lcnt[tid] = 0; lcnt[tid + 256] = 0;
    __syncthreads();
    for (int e = beg + tid; e < end; e += 256) {
        unsigned v = ebuf[e];
        int dloc = v >> 17;
        int pos = beg + lpre[dloc] + atomicAdd(&lcnt[dloc], 1);
        esrc[pos] = (int)(v & 0x1FFFFu);
    }
}

// ---------------- weight convert: f32 [K][N] -> bf16 col-major [N][K] ----------------
__global__ void wconv_kernel(const float* __restrict__ Wg0, const float* __restrict__ Wg1,
                             unsigned short* __restrict__ w0t, unsigned short* __restrict__ w1t) {
    int idx = blockIdx.x * 256 + threadIdx.x;
    if (idx < 128 * 128) {
        int n = idx >> 7, k = idx & 127;
        w0t[n * 128 + k] = f2bf(Wg0[k * 128 + n]);
    } else if (idx < 128 * 128 + 64 * 128) {
        int j = idx - 128 * 128;
        int n = j >> 7, k = j & 127;
        w1t[n * 128 + k] = f2bf(Wg1[k * 64 + n]);
    }
}

// ---------------- encoder: h0 = relu(x @ W_enc + b) -> bf16 packed ----------------
__global__ __launch_bounds__(256) void enc_kernel(const float* __restrict__ x,
                                                  const float* __restrict__ W,
                                                  const float* __restrict__ b,
                                                  unsigned* __restrict__ h0) {
    __shared__ float Wl[16 * 128];
    int tid = threadIdx.x;
    for (int i = tid; i < 16 * 128; i += 256) Wl[i] = W[i];
    __syncthreads();
    int cp = tid & 63;
    int rl = tid >> 6;
    float b0 = b[cp * 2], b1 = b[cp * 2 + 1];
    int row0 = blockIdx.x * 16;
    for (int it = 0; it < 4; it++) {
        int row = row0 + it * 4 + rl;
        if (row < N_NODES) {
            float a0 = b0, a1 = b1;
            #pragma unroll
            for (int k = 0; k < 16; k++) {
                float xv = x[row * 16 + k];
                a0 += xv * Wl[k * 128 + cp * 2];
                a1 += xv * Wl[k * 128 + cp * 2 + 1];
            }
            h0[row * 64 + cp] = pack2(fmaxf(a0, 0.0f), fmaxf(a1, 0.0f));
        }
    }
}

// ---------------- MFMA GEMM: outb[r] = dinv[r]*(h[r] @ W), h bf16 [N][128], Wt bf16 col-major
template <int NOUT>
__global__ __launch_bounds__(256) void mfma_gemm_kernel(const unsigned short* __restrict__ hg,
                                                        const unsigned short* __restrict__ Wt,
                                                        const float* __restrict__ dinv,
                                                        unsigned short* __restrict__ outb) {
    constexpr int PAD = 136;                      // ushorts per LDS row (+16B pad)
    __shared__ unsigned short Wl[NOUT * PAD];
    int tid = threadIdx.x;
    for (int i = tid; i < NOUT * 16; i += 256) {  // 16-byte chunks
        int n = i >> 4, c = i & 15;
        *(float4*)&Wl[n * PAD + c * 8] = *(const float4*)&Wt[n * 128 + c * 8];
    }
    int wave = tid >> 6, lane = tid & 63;
    int m = lane & 15, quad = lane >> 4;
    int row0 = blockIdx.x * 64 + wave * 16;
    int arow = row0 + m;
    bool avalid = arow < N_NODES;
    f32x4 acc[NOUT / 16];
    #pragma unroll
    for (int t = 0; t < NOUT / 16; t++) acc[t] = (f32x4){0.f, 0.f, 0.f, 0.f};
    __syncthreads();
    #pragma unroll
    for (int kc = 0; kc < 4; kc++) {
        bf16x8 af;
        if (avalid) af = *(const bf16x8*)&hg[(size_t)arow * 128 + kc * 32 + quad * 8];
        else af = (bf16x8){0, 0, 0, 0, 0, 0, 0, 0};
        #pragma unroll
        for (int t = 0; t < NOUT / 16; t++) {
            bf16x8 bf = *(const bf16x8*)&Wl[(t * 16 + m) * PAD + kc * 32 + quad * 8];
            acc[t] = __builtin_amdgcn_mfma_f32_16x16x32_bf16(af, bf, acc[t], 0, 0, 0);
        }
    }
    #pragma unroll
    for (int r = 0; r < 4; r++) {
        int row = row0 + quad * 4 + r;
        if (row < N_NODES) {
            float d = dinv[row];
            #pragma unroll
            for (int t = 0; t < NOUT / 16; t++) {
                outb[(size_t)row * NOUT + t * 16 + m] = f2bf(d * acc[t][r]);
            }
        }
    }
}

// ---------------- agg layer1 (F=128): h1 = relu(b + dinv_i * (hws[i] + sum hws[src])) -> bf16
// one wave per node; 4 groups of 16 lanes, each group gathers one edge row (uint4 = 16B/lane)
__global__ __launch_bounds__(256) void agg128_kernel(const unsigned short* __restrict__ hws,
                                                     const int* __restrict__ esrc,
                                                     const int* __restrict__ rowp_end,
                                                     const int* __restrict__ cnt,
                                                     const float* __restrict__ dinv,
                                                     const float* __restrict__ bias,
                                                     unsigned* __restrict__ h1) {
    int wave = threadIdx.x >> 6, lane = threadIdx.x & 63;
    int i = blockIdx.x * 4 + wave;
    if (i >= N_NODES) return;
    int quad = lane >> 4;      // edge group 0..3
    int sub = lane & 15;       // 16B chunk within row
    float di = dinv[i];
    int end = rowp_end[i];
    int start = end - cnt[i];
    float acc[8] = {0.f, 0.f, 0.f, 0.f, 0.f, 0.f, 0.f, 0.f};
    // self term: only group 0 adds it (avoid 4x duplication)
    if (quad == 0) {
        uint4 v = *(const uint4*)&hws[(size_t)i * 128 + sub * 8];
        acc[0] += bf_lo(v.x); acc[1] += bf_hi(v.x);
        acc[2] += bf_lo(v.y); acc[3] += bf_hi(v.y);
        acc[4] += bf_lo(v.z); acc[5] += bf_hi(v.z);
        acc[6] += bf_lo(v.w); acc[7] += bf_hi(v.w);
    }
    int e = start;
    for (; e + 8 <= end; e += 8) {
        int sA = esrc[e + quad];
        int sB = esrc[e + 4 + quad];
        uint4 vA = *(const uint4*)&hws[(size_t)sA * 128 + sub * 8];
        uint4 vB = *(const uint4*)&hws[(size_t)sB * 128 + sub * 8];
        acc[0] += bf_lo(vA.x); acc[1] += bf_hi(vA.x);
        acc[2] += bf_lo(vA.y); acc[3] += bf_hi(vA.y);
        acc[4] += bf_lo(vA.z); acc[5] += bf_hi(vA.z);
        acc[6] += bf_lo(vA.w); acc[7] += bf_hi(vA.w);
        acc[0] += bf_lo(vB.x); acc[1] += bf_hi(vB.x);
        acc[2] += bf_lo(vB.y); acc[3] += bf_hi(vB.y);
        acc[4] += bf_lo(vB.z); acc[5] += bf_hi(vB.z);
        acc[6] += bf_lo(vB.w); acc[7] += bf_hi(vB.w);
    }
    for (; e < end; e += 4) {
        if (quad < end - e) {
            int s = esrc[e + quad];
            uint4 v = *(const uint4*)&hws[(size_t)s * 128 + sub * 8];
            acc[0] += bf_lo(v.x); acc[1] += bf_hi(v.x);
            acc[2] += bf_lo(v.y); acc[3] += bf_hi(v.y);
            acc[4] += bf_lo(v.z); acc[5] += bf_hi(v.z);
            acc[6] += bf_lo(v.w); acc[7] += bf_hi(v.w);
        }
    }
    // fold the 4 edge groups
    #pragma unroll
    for (int j = 0; j < 8; j++) {
        acc[j] += __shfl_xor(acc[j], 16, 64);
        acc[j] += __shfl_xor(acc[j], 32, 64);
    }
    if (quad == 0) {
        float o[8];
        #pragma unroll
        for (int j = 0; j < 8; j++) o[j] = fmaxf(bias[sub * 8 + j] + di * acc[j], 0.0f);
        uint4 pk;
        pk.x = pack2(o[0], o[1]);
        pk.y = pack2(o[2], o[3]);
        pk.z = pack2(o[4], o[5]);
        pk.w = pack2(o[6], o[7]);
        *(uint4*)&h1[(size_t)i * 64 + sub * 4] = pk;
    }
}

// ---------------- agg layer2 (F=64) fused with node scoring ----------------
// 8 groups of 8 lanes; each group gathers one edge row (uint4 = 16B/lane)
__global__ __launch_bounds__(256) void agg64_kernel(const unsigned short* __restrict__ hws,
                                                    const int* __restrict__ esrc,
                                                    const int* __restrict__ rowp_end,
                                                    const int* __restrict__ cnt,
                                                    const float* __restrict__ dinv,
                                                    const float* __restrict__ bias,
                                                    const float* __restrict__ Wsw,
                                                    const float* __restrict__ Wv,
                                                    const float* __restrict__ bv,
                                                    float* __restrict__ aarr,
                                                    float* __restrict__ carr,
                                                    float* __restrict__ outv) {
    int wave = threadIdx.x >> 6, lane = threadIdx.x & 63;
    int i = blockIdx.x * 4 + wave;
    if (i >= N_NODES) return;
    int oct = lane >> 3;       // edge group 0..7
    int sub = lane & 7;        // 16B chunk within row
    float di = dinv[i];
    int end = rowp_end[i];
    int start = end - cnt[i];
    float acc[8] = {0.f, 0.f, 0.f, 0.f, 0.f, 0.f, 0.f, 0.f};
    if (oct == 0) {
        uint4 v = *(const uint4*)&hws[(size_t)i * 64 + sub * 8];
        acc[0] += bf_lo(v.x); acc[1] += bf_hi(v.x);
        acc[2] += bf_lo(v.y); acc[3] += bf_hi(v.y);
        acc[4] += bf_lo(v.z); acc[5] += bf_hi(v.z);
        acc[6] += bf_lo(v.w); acc[7] += bf_hi(v.w);
    }
    for (int e = start; e < end; e += 8) {
        if (oct < end - e) {
            int s = esrc[e + oct];
            uint4 v = *(const uint4*)&hws[(size_t)s * 64 + sub * 8];
            acc[0] += bf_lo(v.x); acc[1] += bf_hi(v.x);
            acc[2] += bf_lo(v.y); acc[3] += bf_hi(v.y);
            acc[4] += bf_lo(v.z); acc[5] += bf_hi(v.z);
            acc[6] += bf_lo(v.w); acc[7] += bf_hi(v.w);
        }
    }
    // fold the 8 edge groups (bits 3,4,5)
    #pragma unroll
    for (int j = 0; j < 8; j++) {
        acc[j] += __shfl_xor(acc[j], 8, 64);
        acc[j] += __shfl_xor(acc[j], 16, 64);
        acc[j] += __shfl_xor(acc[j], 32, 64);
    }
    // features f = sub*8+j, replicated across octs; partial dots then fold bits 0,1,2
    float pa = 0.f, pc = 0.f, pv = 0.f;
    #pragma unroll
    for (int j = 0; j < 8; j++) {
        int f = sub * 8 + j;
        float h = fmaxf(bias[f] + di * acc[j], 0.0f);
        pa += h * Wsw[f];
        pc += h * Wsw[64 + f];
        pv += h * Wv[f];
    }
    #pragma unroll
    for (int m = 1; m <= 4; m <<= 1) {
        pa += __shfl_xor(pa, m, 64);
        pc += __shfl_xor(pc, m, 64);
        pv += __shfl_xor(pv, m, 64);
    }
    if (lane == 0) {
        aarr[i] = pa;
        carr[i] = pc;
        float v = 1.0f / (1.0f + expf(-(pv + bv[0])));
        float t = 0.9f + 0.2f * v;
        float vw = fminf(fmaxf(t * t, 0.81f), 1.21f);
        outv[i] = sqrtf(vw);
    }
}

// ---------------- per-edge switch scores ----------------
__global__ void edge_kernel(const int* __restrict__ eidx, const float* __restrict__ aarr,
                            const float* __restrict__ carr, const float* __restrict__ bsw,
                            float* __restrict__ out) {
    int e = blockIdx.x * 256 + threadIdx.x;
    if (e < N_EDGES) {
        int s = eidx[e], d = eidx[N_EDGES + e];
        float z = aarr[s] + carr[d] + bsw[0];
        float y = 1.0f / (1.0f + expf(-z));
        out[e] = fminf(fmaxf(y, 0.0f), 1.0f);
    }
}

extern "C" void kernel_launch(void* const* d_in, const int* in_sizes, int n_in,
                              void* d_out, int out_size, void* d_ws, size_t ws_size,
                              hipStream_t stream) {
    const float* x     = (const float*)d_in[0];
    const int*   eidx  = (const int*)d_in[1];
    const float* W_enc = (const float*)d_in[2];
    const float* b_enc = (const float*)d_in[3];
    const float* W_g0  = (const float*)d_in[4];
    const float* b_g0  = (const float*)d_in[5];
    const float* W_g1  = (const float*)d_in[6];
    const float* b_g1  = (const float*)d_in[7];
    const float* W_sw  = (const float*)d_in[8];
    const float* b_sw  = (const float*)d_in[9];
    const float* W_v   = (const float*)d_in[10];
    const float* b_v   = (const float*)d_in[11];
    float* out = (float*)d_out;

    char* ws = (char*)d_ws;
    size_t off = 0;
    auto alloc = [&](size_t bytes) {
        void* p = ws + off;
        off = (off + bytes + 255) & ~(size_t)255;
        return p;
    };
    unsigned*       h0   = (unsigned*)alloc((size_t)N_NODES * 64 * 4);        // N x 128 bf16
    unsigned short* hws1 = (unsigned short*)alloc((size_t)N_NODES * 128 * 2); // N x 128 bf16
    unsigned*       h1   = (unsigned*)alloc((size_t)N_NODES * 64 * 4);        // N x 128 bf16
    unsigned short* hws2 = (unsigned short*)alloc((size_t)N_NODES * 64 * 2);  // N x 64 bf16
    int*   cnt  = (int*)alloc((size_t)N_NODES * 4);
    int*   rowp = (int*)alloc((size_t)N_NODES * 4);
    float* dinv = (float*)alloc((size_t)N_NODES * 4);
    float* aarr = (float*)alloc((size_t)N_NODES * 4);
    float* carr = (float*)alloc((size_t)N_NODES * 4);
    int*   esrc = (int*)alloc((size_t)N_EDGES * 4);
    unsigned* ebuf = (unsigned*)alloc((size_t)N_EDGES * 4);
    int*   ghist = (int*)alloc(256 * 4);
    int*   gbase = (int*)alloc(256 * 4);
    int*   gcur  = (int*)alloc(256 * 4);
    unsigned short* w0t = (unsigned short*)alloc(128 * 128 * 2);
    unsigned short* w1t = (unsigned short*)alloc(64 * 128 * 2);

    hipMemsetAsync(ghist, 0, NB * 4, stream);
    hist_kernel<<<NBLK_E, 256, 0, stream>>>(eidx, ghist);
    scanb_kernel<<<1, 256, 0, stream>>>(ghist, gbase, gcur);
    part_kernel<<<NBLK_E, 256, 0, stream>>>(eidx, gcur, ebuf);
    csr_fine_kernel<<<NB, 256, 0, stream>>>(ebuf, gbase, esrc, cnt, rowp, dinv);

    wconv_kernel<<<96, 256, 0, stream>>>(W_g0, W_g1, w0t, w1t);
    enc_kernel<<<(N_NODES + 15) / 16, 256, 0, stream>>>(x, W_enc, b_enc, h0);
    mfma_gemm_kernel<128><<<(N_NODES + 63) / 64, 256, 0, stream>>>((const unsigned short*)h0, w0t, dinv, hws1);
    agg128_kernel<<<(N_NODES + 3) / 4, 256, 0, stream>>>(hws1, esrc, rowp, cnt, dinv, b_g0, h1);
    mfma_gemm_kernel<64><<<(N_NODES + 63) / 64, 256, 0, stream>>>((const unsigned short*)h1, w1t, dinv, hws2);
    agg64_kernel<<<(N_NODES + 3) / 4, 256, 0, stream>>>(hws2, esrc, rowp, cnt, dinv, b_g1,
                                                        W_sw, W_v, b_v, aarr, carr, out + N_EDGES);
    edge_kernel<<<(N_EDGES + 255) / 256, 256, 0, stream>>>(eidx, aarr, carr, b_sw, out);
}